// Round 5
// baseline (394.548 us; speedup 1.0000x reference)
//
#include <hip/hip_runtime.h>
#include <hip/hip_bf16.h>
#include <math.h>

#define NN   10000
#define IND  512
#define HID  256
#define NE   400000
#define KPAD 10240   // adj GEMM K padded
#define SKA  8       // split-K adj GEMM  (KCHA = 1280)
#define KCHA 1280
#define SKX  4       // split-K X@W GEMM  (KCHX = 128)
#define KCHX 128

typedef __attribute__((ext_vector_type(4))) float  f32x4;
typedef __attribute__((ext_vector_type(4))) int    i32x4;
typedef __attribute__((ext_vector_type(2))) uint   u32x2;
typedef __attribute__((ext_vector_type(8))) short  bf16x8;

static __device__ inline ushort f2b(float f) {
    union { __hip_bfloat16 b; ushort u; } c;
    c.b = __float2bfloat16(f);
    return c.u;
}
static __device__ inline float b2f(ushort u) {
    union { uint t; float f; } c;
    c.t = (uint)u << 16;
    return c.f;
}
static __device__ inline void gload_lds16(const void* g, void* l) {
    __builtin_amdgcn_global_load_lds(
        (const __attribute__((address_space(1))) unsigned int*)g,
        (__attribute__((address_space(3))) unsigned int*)l, 16, 0, 0);
}
// pinned-order A prefetch: 2 vmem loads, exact vmcnt accounting
static __device__ inline void aload(const float* p, f32x4& a, f32x4& b) {
    asm volatile("global_load_dwordx4 %0, %2, off\n\t"
                 "global_load_dwordx4 %1, %2, off offset:16"
                 : "=&v"(a), "=&v"(b) : "v"(p) : "memory");
}

// ---------------------------------------------------------------------------
// Transpose + convert: dst[c][r] = bf16(src[r][c]) for r<R else 0.
__global__ __launch_bounds__(256) void tr_cvt(
    const float* __restrict__ src, ushort* __restrict__ dst,
    int R, int C, int Rpad)
{
    __shared__ float t[64][65];
    const int r0 = blockIdx.x * 64, c0 = blockIdx.y * 64;
    const int tx = threadIdx.x & 63, ty = threadIdx.x >> 6;

    #pragma unroll
    for (int i = 0; i < 16; ++i) {
        const int rl = ty * 16 + i;
        const int r  = r0 + rl;
        float v = 0.f;
        if (r < R) v = src[(size_t)r * C + c0 + tx];
        t[rl][tx] = v;
    }
    __syncthreads();
    #pragma unroll
    for (int i = 0; i < 16; ++i) {
        const int cl = ty * 16 + i;
        dst[(size_t)(c0 + cl) * Rpad + r0 + tx] = f2b(t[tx][cl]);
    }
}

// ---------------------------------------------------------------------------
// C[M,256] += A[M, kbeg:kbeg+k_chunk] @ B(chunk) via atomicAdd (C pre-zeroed).
// A f32 (cvt bf16 on the fly), B K-contiguous bf16 BT[256][ld_bt].
// 64x256 block, 4 waves, wave tile 64x64, BK=32, LDS double-buffer,
// counted vmcnt: one "s_waitcnt vmcnt(2) lgkmcnt(0)" + s_barrier per K-step.
__global__ __launch_bounds__(256, 3) void gemm_n256(
    const float* __restrict__ A, const ushort* __restrict__ BT,
    float* __restrict__ C, int M, int K_real, int ld_bt, int lda, int k_chunk)
{
    __shared__ ushort Alds[2][2048];   //  8 KB
    __shared__ ushort Blds[2][8192];   // 32 KB

    const int tid  = threadIdx.x;
    const int lane = tid & 63;
    const int w    = tid >> 6;

    const int gx  = gridDim.x;
    const int nwg = gx * gridDim.y;
    const int lin = blockIdx.y * gx + blockIdx.x;
    const int q = nwg >> 3, r = nwg & 7;
    const int xc = lin & 7, o = lin >> 3;
    const int work = (xc < r ? xc * (q + 1) : r * (q + 1) + (xc - r) * q) + o;
    const int row0 = (work % gx) * 64;
    const int sk   = work / gx;
    const int kbeg = sk * k_chunk;

    const int arow = ((tid >> 6) << 4) | (tid & 15);
    const int akg  = (tid >> 4) & 3;
    const int grow = row0 + arow;
    const bool aok = grow < M;
    const bool lastrow = (grow == M - 1);
    const float* aptr = A + (size_t)grow * lda + kbeg + (akg << 3);

    const ushort* bsrc0 = BT + (size_t)((w << 6) + (lane & 15)) * ld_bt
                             + kbeg + ((lane >> 4) << 3);

    const int nt = k_chunk >> 5;

    f32x4 acc[4][4];
    #pragma unroll
    for (int i = 0; i < 4; ++i)
        #pragma unroll
        for (int j = 0; j < 4; ++j)
            acc[i][j] = (f32x4){0.f, 0.f, 0.f, 0.f};

    auto apick = [&](int kn) -> const float* {
        const bool ok = aok && (kn < k_chunk) &&
                        (!lastrow || (kbeg + kn + (akg << 3) + 8) <= K_real);
        return ok ? (aptr + kn) : A;
    };

    f32x4 va0, va1;
    // ---- prologue: stage tile 0 into buf0, prefetch A(tile1) ----
    aload(apick(0), va0, va1);
    asm volatile("s_waitcnt vmcnt(0)" ::: "memory");
    __builtin_amdgcn_sched_barrier(0);
    {
        union { ushort u[8]; i32x4 v4; } pk;
        pk.u[0]=f2b(va0.x); pk.u[1]=f2b(va0.y); pk.u[2]=f2b(va0.z); pk.u[3]=f2b(va0.w);
        pk.u[4]=f2b(va1.x); pk.u[5]=f2b(va1.y); pk.u[6]=f2b(va1.z); pk.u[7]=f2b(va1.w);
        *reinterpret_cast<i32x4*>(&Alds[0][tid << 3]) = pk.v4;
    }
    #pragma unroll
    for (int g = 0; g < 4; ++g)
        gload_lds16(bsrc0 + (size_t)(g << 4) * ld_bt,
                    &Blds[0][((w << 2) + g) << 9]);
    aload(apick(32), va0, va1);
    asm volatile("s_waitcnt vmcnt(2) lgkmcnt(0)" ::: "memory");
    __builtin_amdgcn_s_barrier();

    // ---- main loop: compute tile t (buf t&1), stage tile t+1 ----
    for (int t = 0; t < nt - 1; ++t) {
        const int cur = t & 1;
        asm volatile("s_waitcnt vmcnt(0)" ::: "memory");   // A(t+1) ready
        __builtin_amdgcn_sched_barrier(0);
        {
            union { ushort u[8]; i32x4 v4; } pk;
            pk.u[0]=f2b(va0.x); pk.u[1]=f2b(va0.y); pk.u[2]=f2b(va0.z); pk.u[3]=f2b(va0.w);
            pk.u[4]=f2b(va1.x); pk.u[5]=f2b(va1.y); pk.u[6]=f2b(va1.z); pk.u[7]=f2b(va1.w);
            *reinterpret_cast<i32x4*>(&Alds[cur ^ 1][tid << 3]) = pk.v4;
        }
        const int k1 = (t + 1) << 5;
        #pragma unroll
        for (int g = 0; g < 4; ++g)
            gload_lds16(bsrc0 + (size_t)(g << 4) * ld_bt + k1,
                        &Blds[cur ^ 1][((w << 2) + g) << 9]);
        aload(apick((t + 2) << 5), va0, va1);

        bf16x8 bfr[4];
        #pragma unroll
        for (int nf = 0; nf < 4; ++nf)
            bfr[nf] = *reinterpret_cast<const bf16x8*>(
                &Blds[cur][((((w << 2) + nf) << 6) | lane) << 3]);
        #pragma unroll
        for (int mf = 0; mf < 4; ++mf) {
            const bf16x8 af = *reinterpret_cast<const bf16x8*>(
                &Alds[cur][((mf << 6) | lane) << 3]);
            #pragma unroll
            for (int nf = 0; nf < 4; ++nf)
                acc[mf][nf] = __builtin_amdgcn_mfma_f32_16x16x32_bf16(
                    af, bfr[nf], acc[mf][nf], 0, 0, 0);
        }
        asm volatile("s_waitcnt vmcnt(2) lgkmcnt(0)" ::: "memory");
        __builtin_amdgcn_s_barrier();
    }

    // ---- peeled last tile ----
    {
        const int cur = (nt - 1) & 1;
        bf16x8 bfr[4];
        #pragma unroll
        for (int nf = 0; nf < 4; ++nf)
            bfr[nf] = *reinterpret_cast<const bf16x8*>(
                &Blds[cur][((((w << 2) + nf) << 6) | lane) << 3]);
        #pragma unroll
        for (int mf = 0; mf < 4; ++mf) {
            const bf16x8 af = *reinterpret_cast<const bf16x8*>(
                &Alds[cur][((mf << 6) | lane) << 3]);
            #pragma unroll
            for (int nf = 0; nf < 4; ++nf)
                acc[mf][nf] = __builtin_amdgcn_mfma_f32_16x16x32_bf16(
                    af, bfr[nf], acc[mf][nf], 0, 0, 0);
        }
    }

    // epilogue: atomic accumulate; col = lane&15, row = base + (lane>>4)*4 + rr
    #pragma unroll
    for (int mf = 0; mf < 4; ++mf) {
        const int rbase = row0 + mf * 16 + ((lane >> 4) << 2);
        #pragma unroll
        for (int nf = 0; nf < 4; ++nf) {
            const int col = (w << 6) + nf * 16 + (lane & 15);
            #pragma unroll
            for (int rr = 0; rr < 4; ++rr) {
                const int row = rbase + rr;
                if (row < M) atomicAdd(&C[(size_t)row * HID + col], acc[mf][nf][rr]);
            }
        }
    }
}

// ---------------------------------------------------------------------------
__global__ void k_uv(const float* __restrict__ W2, const float* __restrict__ W3,
                     float* __restrict__ c)
{
    const int j = blockIdx.x * blockDim.x + threadIdx.x;
    if (j >= 2 * HID) return;
    float s = 0.f;
    for (int m = 0; m < HID; ++m)
        s = fmaf(W2[(size_t)j * HID + m], W3[m], s);
    c[j] = s;
}

// ---------------------------------------------------------------------------
__global__ __launch_bounds__(256) void k_node(
    const float* __restrict__ z, const float* __restrict__ c,
    const float* __restrict__ W3, ushort* __restrict__ zb,
    ushort* __restrict__ zsb, float* __restrict__ av, float* __restrict__ bv)
{
    const int node = (int)((blockIdx.x * blockDim.x + threadIdx.x) >> 6);
    const int lane = threadIdx.x & 63;
    if (node >= NN) return;

    const f32x4 s = *reinterpret_cast<const f32x4*>(&z[(size_t)node * HID + (lane << 2)]);
    const f32x4 w4 = *reinterpret_cast<const f32x4*>(&W3[HID + (lane << 2)]);
    const f32x4 u4 = *reinterpret_cast<const f32x4*>(&c[(lane << 2)]);
    const f32x4 v4 = *reinterpret_cast<const f32x4*>(&c[HID + (lane << 2)]);
    const f32x4 zs4 = s * w4;

    union { ushort u[4]; u32x2 v; } pz, ps;
    pz.u[0] = f2b(s.x);   pz.u[1] = f2b(s.y);
    pz.u[2] = f2b(s.z);   pz.u[3] = f2b(s.w);
    ps.u[0] = f2b(zs4.x); ps.u[1] = f2b(zs4.y);
    ps.u[2] = f2b(zs4.z); ps.u[3] = f2b(zs4.w);
    *reinterpret_cast<u32x2*>(&zb [(size_t)node * HID + (lane << 2)]) = pz.v;
    *reinterpret_cast<u32x2*>(&zsb[(size_t)node * HID + (lane << 2)]) = ps.v;

    const float r0 = fmaxf(s.x, 0.f), r1 = fmaxf(s.y, 0.f);
    const float r2 = fmaxf(s.z, 0.f), r3 = fmaxf(s.w, 0.f);
    float pa = r0 * u4.x + r1 * u4.y + r2 * u4.z + r3 * u4.w;
    float pb = r0 * v4.x + r1 * v4.y + r2 * v4.z + r3 * v4.w;

    #pragma unroll
    for (int off = 32; off; off >>= 1) {
        pa += __shfl_down(pa, off);
        pb += __shfl_down(pb, off);
    }
    if (lane == 0) { av[node] = pa; bv[node] = pb; }
}

// ---------------------------------------------------------------------------
__global__ __launch_bounds__(256) void k_edge(
    const int* __restrict__ e1, const int* __restrict__ e2,
    const ushort* __restrict__ zb, const ushort* __restrict__ zsb,
    const float* __restrict__ av, const float* __restrict__ bv,
    float* __restrict__ out)
{
    const long long wid = (((long long)blockIdx.x * blockDim.x) + threadIdx.x) >> 6;
    const int lane = threadIdx.x & 63;
    const int half = lane >> 5;
    const int l32  = lane & 31;
    const long long e = 2LL * wid + half;
    if (e >= 2LL * NE) return;

    const int* ep = (e < NE) ? &e1[2 * (int)e] : &e2[2 * ((int)e - NE)];
    const int i = ep[0];
    const int j = ep[1];

    const bf16x8 zi = *reinterpret_cast<const bf16x8*>(&zsb[(size_t)i * HID + (l32 << 3)]);
    const bf16x8 zj = *reinterpret_cast<const bf16x8*>(&zb [(size_t)j * HID + (l32 << 3)]);
    float p = 0.f;
    #pragma unroll
    for (int t = 0; t < 8; ++t)
        p = fmaf(b2f((ushort)zi[t]), b2f((ushort)zj[t]), p);

    #pragma unroll
    for (int m = 16; m; m >>= 1)
        p += __shfl_xor(p, m);

    if (l32 == 0) {
        const float logit = av[i] + bv[j] + p;
        out[e] = 1.f / (1.f + expf(-logit));
    }
}

// ---------------------------------------------------------------------------
extern "C" void kernel_launch(void* const* d_in, const int* in_sizes, int n_in,
                              void* d_out, int out_size, void* d_ws, size_t ws_size,
                              hipStream_t stream)
{
    const float* X   = (const float*)d_in[0];
    const float* adj = (const float*)d_in[1];
    const int*   e1  = (const int*)d_in[2];
    const int*   e2  = (const int*)d_in[3];
    const float* W   = (const float*)d_in[4];
    const float* W2  = (const float*)d_in[5];
    const float* W3  = (const float*)d_in[6];
    float* out = (float*)d_out;

    float*  ws   = (float*)d_ws;
    float*  a    = ws;                                   // NN
    float*  b    = a + NN;                               // NN
    float*  c    = b + NN;                               // 512
    float*  XW   = c + 512;                              // NN*HID f32
    float*  z    = XW + (size_t)NN * HID;                // NN*HID f32
    ushort* WTb  = (ushort*)(z + (size_t)NN * HID);      // HID*IND
    ushort* XWbT = WTb  + (size_t)HID * IND;             // HID*KPAD
    ushort* zb   = XWbT + (size_t)HID * KPAD;            // NN*HID
    ushort* zsb  = zb   + (size_t)NN * HID;              // NN*HID

    const dim3 blk(256);

    hipMemsetAsync(XW, 0, (size_t)NN * HID * 4, stream);
    hipMemsetAsync(z,  0, (size_t)NN * HID * 4, stream);

    tr_cvt<<<dim3(IND / 64, HID / 64), blk, 0, stream>>>(W, WTb, IND, HID, IND);

    gemm_n256<<<dim3(157, SKX), blk, 0, stream>>>(X, WTb, XW, NN, IND, IND, IND, KCHX);

    tr_cvt<<<dim3(KPAD / 64, HID / 64), blk, 0, stream>>>(XW, XWbT, NN, HID, KPAD);

    gemm_n256<<<dim3(157, SKA), blk, 0, stream>>>(adj, XWbT, z, NN, NN, KPAD, NN, KCHA);

    k_uv<<<dim3(2), blk, 0, stream>>>(W2, W3, c);

    k_node<<<dim3((NN * 64) / 256), blk, 0, stream>>>(z, c, W3, zb, zsb, a, b);

    k_edge<<<dim3((NE * 64) / 256), blk, 0, stream>>>(e1, e2, zb, zsb, a, b, out);
}